// Round 19
// baseline (223.630 us; speedup 1.0000x reference)
//
#include <hip/hip_runtime.h>

// ---------------- problem dims ----------------
#define NB   16
#define TT   2000
#define TP   2048      // padded T for GEMM tiling
#define SPT  2048      // spart row stride (padded for float4 loads)
#define ENC  512
#define ATTD 512
#define HH   4
#define CC   10
#define KK   64        // conv half-window
#define KW   129       // 2K+1
#define HATT 2048

typedef unsigned short u16;
typedef __attribute__((ext_vector_type(8))) short bf16x8;
typedef __attribute__((ext_vector_type(4))) float f32x4;

#define AS1 __attribute__((address_space(1)))
#define AS3 __attribute__((address_space(3)))

// convert geometry: 2176 blocks x 256 thr x 4 chunks x 8 elem
//   = 17,825,792 = NB*TP*ENC (1<<24) + 2048*512 (Wk) exactly
#define CVT_BLOCKS   2176
#define CVT_THREADS  (CVT_BLOCKS * 256)

// round-to-nearest-even f32 -> bf16, packed pair
__device__ inline unsigned bfpack2(float lo, float hi) {
    unsigned a = __builtin_bit_cast(unsigned, lo);
    unsigned b = __builtin_bit_cast(unsigned, hi);
    a = (a + 0x7fffu + ((a >> 16) & 1u)) >> 16;
    b = (b + 0x7fffu + ((b >> 16) & 1u)) >> 16;
    return a | (b << 16);
}

// ---------------- 1. fused prep: convert + conv_f(->bf16 f^T) + dec + Wa pack --
__global__ __launch_bounds__(256) void prep_kernel(
    const float* __restrict__ enc, const float* __restrict__ Wk,
    const float* __restrict__ ali_prev, const float* __restrict__ WF,
    const float* __restrict__ bF, const float* __restrict__ dec_prev,
    const float* __restrict__ Wd, const float* __restrict__ Wa,
    const int* __restrict__ enc_len,
    u16* __restrict__ Abf, u16* __restrict__ Wkbf,
    u16* __restrict__ ftb, u16* __restrict__ wab,
    float* __restrict__ decp)
{
    __shared__ union {
        struct { float aliW[632]; float wfT[KW * CC]; float bfs[CC]; } cv;
        float dsl[16 * 128];
    } sm;
    const int bid = blockIdx.x, tid = threadIdx.x;

    if (bid < CVT_BLOCKS) {
        // ---- bf16 convert; issue all 4 chunk loads before converts/stores ----
        const long long ATOT = (long long)NB * TP * ENC;   // 1<<24
        f32x4 v[4][2];
        bool live[4];
        long long g[4];
        #pragma unroll
        for (int it = 0; it < 4; it++) {
            long long cid = (long long)it * CVT_THREADS + bid * 256 + tid;
            long long gid = cid * 8;
            g[it] = gid;
            const float* s;
            bool valid = true;
            if (gid < ATOT) {
                int n = (int)(gid >> 20);
                int rem = (int)(gid & ((1 << 20) - 1));
                int r = rem >> 9, e = rem & 511;
                valid = (r < enc_len[n]);   // wave-uniform (one row per wave)
                s = enc + ((long long)n * TT + r) * ENC + e;
            } else {
                s = Wk + (gid - ATOT);      // < 2048*512
            }
            live[it] = valid;
            if (valid) {
                v[it][0] = __builtin_nontemporal_load((const f32x4*)s);
                v[it][1] = __builtin_nontemporal_load((const f32x4*)s + 1);
            }
        }
        #pragma unroll
        for (int it = 0; it < 4; it++) {
            if (!live[it]) continue;
            uint4 out;
            out.x = bfpack2(v[it][0].x, v[it][0].y);
            out.y = bfpack2(v[it][0].z, v[it][0].w);
            out.z = bfpack2(v[it][1].x, v[it][1].y);
            out.w = bfpack2(v[it][1].z, v[it][1].w);
            if (g[it] < ATOT) *(uint4*)(Abf + g[it]) = out;
            else              *(uint4*)(Wkbf + (g[it] - ATOT)) = out;
        }
    } else if (bid < CVT_BLOCKS + 256) {
        // ---- grouped conv1d, register accumulators; writes ftb[t][16] bf16 ----
        int b2 = bid - CVT_BLOCKS;
        int tc = b2 & 3, h = (b2 >> 2) & 3, n = b2 >> 4;
        int t0 = tc * 500;
        float* aliW = sm.cv.aliW;
        float* wfT  = sm.cv.wfT;       // [k][c] layout
        float* bfs  = sm.cv.bfs;
        const float* arow = ali_prev + ((long long)n * HH + h) * TT;
        for (int i = tid; i < 632; i += 256) {
            int tt = t0 - KK + i;
            aliW[i] = (tt >= 0 && tt < TT) ? arow[tt] : 0.f;
        }
        for (int i = tid; i < KW * CC; i += 256) {
            int k = i / CC, c = i - k * CC;
            wfT[i] = WF[(h * CC + c) * KW + k];
        }
        if (tid < CC) bfs[tid] = bF[h * CC + tid];
        __syncthreads();
        if (tid < 250) {
            float acc0[CC], acc1[CC];
            #pragma unroll
            for (int c = 0; c < CC; c++) { acc0[c] = 0.f; acc1[c] = 0.f; }
            const int base = 2 * tid;
            float2 w0 = *(const float2*)&aliW[base];
            for (int k = 0; k < 128; k += 2) {
                float2 w2 = *(const float2*)&aliW[base + k + 2];
                #pragma unroll
                for (int cj = 0; cj < 5; cj++) {
                    float2 fk  = *(const float2*)&wfT[k * CC + cj * 2];
                    float2 fk1 = *(const float2*)&wfT[(k + 1) * CC + cj * 2];
                    acc0[2*cj]   += w0.x * fk.x + w0.y * fk1.x;
                    acc0[2*cj+1] += w0.x * fk.y + w0.y * fk1.y;
                    acc1[2*cj]   += w0.y * fk.x + w2.x * fk1.x;
                    acc1[2*cj+1] += w0.y * fk.y + w2.x * fk1.y;
                }
                w0 = w2;
            }
            #pragma unroll
            for (int cj = 0; cj < 5; cj++) {
                float2 fk = *(const float2*)&wfT[128 * CC + cj * 2];
                acc0[2*cj]   += w0.x * fk.x;  acc0[2*cj+1] += w0.x * fk.y;
                acc1[2*cj]   += w0.y * fk.x;  acc1[2*cj+1] += w0.y * fk.y;
            }
            #pragma unroll
            for (int c = 0; c < CC; c++) { acc0[c] += bfs[c]; acc1[c] += bfs[c]; }
            int t = t0 + base;
            u16* frow = ftb + (((long long)(n * HH + h)) * TP + t) * 16;
            uint4 ra, rb;
            ra.x = bfpack2(acc0[0], acc0[1]); ra.y = bfpack2(acc0[2], acc0[3]);
            ra.z = bfpack2(acc0[4], acc0[5]); ra.w = bfpack2(acc0[6], acc0[7]);
            rb.x = bfpack2(acc0[8], acc0[9]); rb.y = 0u; rb.z = 0u; rb.w = 0u;
            *(uint4*)(frow)     = ra; *(uint4*)(frow + 8)  = rb;
            ra.x = bfpack2(acc1[0], acc1[1]); ra.y = bfpack2(acc1[2], acc1[3]);
            ra.z = bfpack2(acc1[4], acc1[5]); ra.w = bfpack2(acc1[6], acc1[7]);
            rb.x = bfpack2(acc1[8], acc1[9]);
            *(uint4*)(frow + 16) = ra; *(uint4*)(frow + 24) = rb;
        } else if (tc == 3) {
            // zero-pad ftb rows t in [2000, 2048)
            uint4 z = {0u, 0u, 0u, 0u};
            int r0 = 2000 + (tid - 250) * 8;
            u16* frow = ftb + (((long long)(n * HH + h)) * TP + r0) * 16;
            for (int r = 0; r < 8; r++) {
                *(uint4*)(frow + r * 16)     = z;
                *(uint4*)(frow + r * 16 + 8) = z;
            }
        }
    } else if (bid < CVT_BLOCKS + 288) {
        // ---- dec_part K-split partials: decp[kc][n][d] ----
        int b2 = bid - (CVT_BLOCKS + 256);   // 0..31
        int kc = b2 >> 3, jc = b2 & 7;
        for (int i = tid; i < 2048; i += 256) {
            int nn = i >> 7, kk = i & 127;
            sm.dsl[i] = dec_prev[nn * 512 + kc * 128 + kk];
        }
        __syncthreads();
        int d = jc * 256 + tid;
        float acc[NB];
        #pragma unroll
        for (int n = 0; n < NB; n++) acc[n] = 0.f;
        const float4* w4 = (const float4*)(Wd + (long long)d * 512 + kc * 128);
        for (int e4 = 0; e4 < 32; e4++) {
            float4 w = w4[e4];
            #pragma unroll
            for (int n = 0; n < NB; n++) {
                const float* a = sm.dsl + n * 128 + e4 * 4;
                acc[n] += w.x * a[0] + w.y * a[1] + w.z * a[2] + w.w * a[3];
            }
        }
        #pragma unroll
        for (int n = 0; n < NB; n++) decp[((long long)kc * NB + n) * HATT + d] = acc[n];
    } else {
        // ---- wab[j][16] = Wa[j>>9][j&511][0..9] bf16 (B-ext rows) ----
        int b2 = bid - (CVT_BLOCKS + 288);   // 0..3
        int j0 = b2 * 512 + tid * 2;
        #pragma unroll
        for (int q = 0; q < 2; q++) {
            int j = j0 + q;
            int hh = j >> 9, dd = j & 511;
            const float* wr = Wa + ((long long)(hh * ATTD + dd)) * CC;
            uint4 ra, rb;
            ra.x = bfpack2(wr[0], wr[1]); ra.y = bfpack2(wr[2], wr[3]);
            ra.z = bfpack2(wr[4], wr[5]); ra.w = bfpack2(wr[6], wr[7]);
            rb.x = bfpack2(wr[8], wr[9]); rb.y = 0u; rb.z = 0u; rb.w = 0u;
            u16* out = wab + (long long)j * 16;
            *(uint4*)(out)     = ra;
            *(uint4*)(out + 8) = rb;
        }
    }
}

// ---------------- 2. persistent fused GEMM (grid 1024, 4 logical tiles/block) --
// logical id = blockIdx.x + it*1024 (same XCD residue; same nt across its ->
// B-panel stays L2-hot); balanced swizzle; ext tiles in regs; (256,4) no spill
__global__ __launch_bounds__(256, 4) void score_gemm_kernel(
    const u16* __restrict__ Abf, const u16* __restrict__ Bbf,
    const u16* __restrict__ ftb, const u16* __restrict__ wab,
    const float* __restrict__ decp, const float* __restrict__ Ww,
    const int* __restrict__ enc_len, float* __restrict__ score_part)
{
    __shared__ __attribute__((aligned(16))) char smem[32768];  // lA 16K | lB 16K
    float* sred = (float*)smem;      // reused after final barrier

    const int tid = threadIdx.x, wave = tid >> 6, lane = tid & 63;
    const int l16 = lane & 15, lk = lane >> 4;
    const int wrow = (wave >> 1) * 64, wcol = (wave & 1) * 64;

    for (int it = 0; it < 4; it++) {
        const int lbid = blockIdx.x + it * 1024;
        const int xcd = lbid & 7;            // == blockIdx.x & 7 (physical XCD)
        const int lcl = lbid >> 3;           // 0..511
        const int nt = lcl & 15;
        const int rr = lcl >> 4;             // 0..31
        const int n = rr >> 1, half = rr & 1;
        const int mtl = (xcd + n) & 7;
        const int mt = half ? (8 + mtl) : mtl;

        if (mt * 128 < enc_len[n]) {         // block-uniform condition
            const int h = nt >> 2;
            const u16* Aptr = Abf + ((long long)n * TP + mt * 128) * ENC;
            const u16* Bptr = Bbf + (long long)nt * 128 * ENC;

            f32x4 acc[4][4];
            #pragma unroll
            for (int mi = 0; mi < 4; mi++)
                #pragma unroll
                for (int nj = 0; nj < 4; nj++) {
                    f32x4 z = {0.f, 0.f, 0.f, 0.f};
                    acc[mi][nj] = z;
                }

            const int t0 = mt * 128, dd0 = (nt & 3) * 128;

            for (int kt = 0; kt < 8; kt++) {
                const int k0 = kt * 64;
                #pragma unroll
                for (int i = 0; i < 4; i++) {
                    int b = i * 4096 + tid * 16;
                    int r = b >> 7, kb = b & 127;
                    int kbs = kb ^ ((r & 7) << 4);
                    __builtin_amdgcn_global_load_lds(
                        (const AS1 void*)(Aptr + r * ENC + k0 + (kbs >> 1)),
                        (AS3 void*)(smem + i * 4096 + wave * 1024), 16, 0, 0);
                    __builtin_amdgcn_global_load_lds(
                        (const AS1 void*)(Bptr + r * ENC + k0 + (kbs >> 1)),
                        (AS3 void*)(smem + 16384 + i * 4096 + wave * 1024), 16, 0, 0);
                }
                __syncthreads();
                #pragma unroll
                for (int ks = 0; ks < 64; ks += 32) {
                    bf16x8 af[4], bf[4];
                    #pragma unroll
                    for (int mi = 0; mi < 4; mi++) {
                        int row = wrow + mi * 16 + l16;
                        int cb = (ks * 2 + lk * 16) ^ ((row & 7) << 4);
                        af[mi] = *(const bf16x8*)(smem + row * 128 + cb);
                    }
                    #pragma unroll
                    for (int nj = 0; nj < 4; nj++) {
                        int row = wcol + nj * 16 + l16;
                        int cb = (ks * 2 + lk * 16) ^ ((row & 7) << 4);
                        bf[nj] = *(const bf16x8*)(smem + 16384 + row * 128 + cb);
                    }
                    #pragma unroll
                    for (int mi = 0; mi < 4; mi++)
                        #pragma unroll
                        for (int nj = 0; nj < 4; nj++)
                            acc[mi][nj] = __builtin_amdgcn_mfma_f32_16x16x32_bf16(
                                af[mi], bf[nj], acc[mi][nj], 0, 0, 0);
                }
                __syncthreads();
            }

            // ---- K-extension step: att fold; ext fragments straight to regs ----
            {
                bf16x8 zer = {0, 0, 0, 0, 0, 0, 0, 0};
                bf16x8 af[4], bf[4];
                #pragma unroll
                for (int mi = 0; mi < 4; mi++) af[mi] = zer;
                #pragma unroll
                for (int nj = 0; nj < 4; nj++) bf[nj] = zer;
                if (lk < 2) {
                    #pragma unroll
                    for (int mi = 0; mi < 4; mi++)
                        af[mi] = *(const bf16x8*)(ftb +
                            (((long long)(n * HH + h)) * TP + t0 + wrow + mi * 16 + l16) * 16 + lk * 8);
                    #pragma unroll
                    for (int nj = 0; nj < 4; nj++)
                        bf[nj] = *(const bf16x8*)(wab +
                            ((long long)(nt * 128 + wcol + nj * 16 + l16)) * 16 + lk * 8);
                }
                #pragma unroll
                for (int mi = 0; mi < 4; mi++)
                    #pragma unroll
                    for (int nj = 0; nj < 4; nj++)
                        acc[mi][nj] = __builtin_amdgcn_mfma_f32_16x16x32_bf16(
                            af[mi], bf[nj], acc[mi][nj], 0, 0, 0);
            }

            // ---- epilogue: score'= sum_d -2*ww*rcp(exp(2v)+1) ----
            float wm2[4], dec4[4];
            #pragma unroll
            for (int nj = 0; nj < 4; nj++) {
                int cl = wcol + nj * 16 + l16;
                wm2[nj] = -2.f * Ww[h * ATTD + dd0 + cl];
                int j = nt * 128 + cl;
                dec4[nj] = decp[((long long)0 * NB + n) * HATT + j]
                         + decp[((long long)1 * NB + n) * HATT + j]
                         + decp[((long long)2 * NB + n) * HATT + j]
                         + decp[((long long)3 * NB + n) * HATT + j];
            }

            #pragma unroll
            for (int mi = 0; mi < 4; mi++) {
                #pragma unroll
                for (int j = 0; j < 4; j++) {
                    int rl = wrow + mi * 16 + lk * 4 + j;
                    float s = 0.f;
                    #pragma unroll
                    for (int nj = 0; nj < 4; nj++) {
                        float v = acc[mi][nj][j] + dec4[nj];
                        float e = __expf(v + v);
                        s = fmaf(wm2[nj], __builtin_amdgcn_rcpf(e + 1.f), s);
                    }
                    s += __shfl_xor(s, 1); s += __shfl_xor(s, 2);
                    s += __shfl_xor(s, 4); s += __shfl_xor(s, 8);
                    if (l16 == 0) sred[(wave & 1) * 128 + rl] = s;
                }
            }
            __syncthreads();
            if (tid < 128) {
                int t = t0 + tid;
                if (t < TT)
                    score_part[((long long)((nt & 3) * NB + n) * HH + h) * SPT + t] =
                        sred[tid] + sred[128 + tid];
            }
        }
        __syncthreads();   // separate iterations: sred reads done before next stage
    }
}

// ---------------- 3. smax_part: partial (max,sum) + summed-score write ---------
// grid 256 = n(16) x h(4) x qr(4); each thread owns 2 consecutive t
__global__ __launch_bounds__(256) void smax_part_kernel(
    const float* __restrict__ score_part, const int* __restrict__ enc_len,
    float* __restrict__ mstat, float* __restrict__ scr)
{
    int qr = blockIdx.x & 3, h = (blockIdx.x >> 2) & 3, n = blockIdx.x >> 4;
    int len = enc_len[n];
    int tid = threadIdx.x;
    int t = qr * 512 + tid * 2;
    float s0 = 0.f, s1 = 0.f;
    #pragma unroll
    for (int q = 0; q < 4; q++) {
        float2 sv = *(const float2*)(score_part +
            (((long long)(q * NB + n)) * HH + h) * SPT + t);
        s0 += sv.x; s1 += sv.y;
    }
    {
        float2 o = {s0, s1};
        *(float2*)(scr + (n * HH + h) * SPT + t) = o;   // summed score for a_enc
    }
    bool v0 = (t < len), v1 = (t + 1 < len);
    float lmax = -3.4e38f;
    if (v0) lmax = s0;
    if (v1) lmax = fmaxf(lmax, s1);
    __shared__ float red[256];
    red[tid] = lmax; __syncthreads();
    for (int off = 128; off; off >>= 1) {
        if (tid < off) red[tid] = fmaxf(red[tid], red[tid + off]);
        __syncthreads();
    }
    float bmax = red[0];
    __syncthreads();
    float lsum = 0.f;
    if (v0) lsum += expf(s0 - bmax);
    if (v1) lsum += expf(s1 - bmax);
    red[tid] = lsum; __syncthreads();
    for (int off = 128; off; off >>= 1) {
        if (tid < off) red[tid] += red[tid + off];
        __syncthreads();
    }
    if (tid == 0) {
        float2 o = {bmax, red[0]};
        *(float2*)(mstat + ((n * HH + h) * 4 + qr) * 2) = o;
    }
}

// ---------------- 4. a_enc + inline softmax finish + ali write -----------------
// grid 512 = n(16) x tc(32); reads pre-summed scr (1 load instead of 4)
__global__ __launch_bounds__(256) void a_enc_kernel(
    const float* __restrict__ scr, const float* __restrict__ mstat,
    const u16* __restrict__ Abf, const int* __restrict__ enc_len,
    float* __restrict__ aep, float* __restrict__ ali)
{
    int tc = blockIdx.x & 31, n = blockIdx.x >> 5;
    int tid = threadIdx.x;
    int len = enc_len[n];
    int tbeg = tc * 63;
    int cnt = len - tbeg; if (cnt > 63) cnt = 63; if (cnt < 0) cnt = 0;
    __shared__ float aliS[HH][64];
    __shared__ float red[2][4][129];   // [tq][k][lane] transposed: conflict-free
    {
        int hh = tid >> 6, tt = tid & 63;
        int t = tbeg + tt;
        const float2* ms = (const float2*)(mstat) + (n * HH + hh) * 4;
        float2 p0 = ms[0], p1 = ms[1], p2 = ms[2], p3 = ms[3];
        float gm = fmaxf(fmaxf(p0.x, p1.x), fmaxf(p2.x, p3.x));
        float gs = p0.y * expf(p0.x - gm) + p1.y * expf(p1.x - gm)
                 + p2.y * expf(p2.x - gm) + p3.y * expf(p3.x - gm);
        float gi = 1.f / gs;
        float av = 0.f;
        if (tt < cnt) {
            float s = scr[(n * HH + hh) * SPT + t];
            av = expf(s - gm) * gi;
        }
        aliS[hh][tt] = av;
        if (tt < 63 && t < TT)
            ali[((long long)n * HH + hh) * TT + t] = av;
    }
    __syncthreads();
    const int l = tid & 127, tq = tid >> 7;   // dims 4l..4l+3; rows tl = 2*ii+tq
    float acc[HH][4];
    #pragma unroll
    for (int hh = 0; hh < HH; hh++)
        #pragma unroll
        for (int k = 0; k < 4; k++) acc[hh][k] = 0.f;
    #pragma unroll 4
    for (int ii = 0; ii < 32; ii++) {
        int tl = ii * 2 + tq;
        if (tl < cnt) {   // explicit guard: never touch unconverted rows
            uint2 u = *(const uint2*)(Abf + ((long long)n * TP + tbeg + tl) * ENC + l * 4);
            float e0 = __builtin_bit_cast(float, u.x << 16);
            float e1 = __builtin_bit_cast(float, u.x & 0xffff0000u);
            float e2 = __builtin_bit_cast(float, u.y << 16);
            float e3 = __builtin_bit_cast(float, u.y & 0xffff0000u);
            #pragma unroll
            for (int hh = 0; hh < HH; hh++) {
                float w = aliS[hh][tl];
                acc[hh][0] += w * e0; acc[hh][1] += w * e1;
                acc[hh][2] += w * e2; acc[hh][3] += w * e3;
            }
        }
    }
    #pragma unroll
    for (int hh = 0; hh < HH; hh++) {
        __syncthreads();
        #pragma unroll
        for (int k = 0; k < 4; k++) red[tq][k][l] = acc[hh][k];
        __syncthreads();
        int d2 = tid * 2;
        float v0 = red[0][d2 & 3][d2 >> 2] + red[1][d2 & 3][d2 >> 2];
        int d3 = d2 + 1;
        float v1 = red[0][d3 & 3][d3 >> 2] + red[1][d3 & 3][d3 >> 2];
        float2 o = {v0, v1};
        *(float2*)(aep + (((long long)tc * NB + n) * HH + hh) * ENC + d2) = o;
    }
}

// ---------------- 4b. reduce1: aep[32][16][4][512] -> aep2[16][4][512] ---------
__global__ __launch_bounds__(256) void reduce1_kernel(
    const float* __restrict__ aep, float* __restrict__ aep2)
{
    int i = blockIdx.x * 256 + threadIdx.x;   // < 32768
    float s = 0.f;
    for (int tc = 0; tc < 32; tc++)
        s += aep[(long long)tc * 32768 + i];
    aep2[i] = s;
}

// ---------------- 5. ctx_tmp partials (grid 256 = kc 8 x jc 32) ----------------
__global__ __launch_bounds__(256) void ctx_tmp_kernel(
    const float* __restrict__ aep2, const float* __restrict__ We,
    const float* __restrict__ be, float* __restrict__ ctmp)
{
    int kc = blockIdx.x >> 5, jc = blockIdx.x & 31;  // kc 0..7 (64-K), jc 0..31
    int tid = threadIdx.x;
    int h = (jc * 64) >> 9;               // uniform per block (64 j per block)
    __shared__ float aes[16 * 64];
    for (int i = tid; i < 1024; i += 256) {
        int nn = i >> 6, kk = i & 63;
        aes[i] = aep2[(nn * HH + h) * ENC + kc * 64 + kk];
    }
    __syncthreads();
    int j = jc * 64 + (tid & 63);
    int ng = tid >> 6;                    // n-group: n = ng*4 .. ng*4+3
    float acc[4];
    #pragma unroll
    for (int n2 = 0; n2 < 4; n2++) acc[n2] = 0.f;
    const float4* w4 = (const float4*)(We + (long long)j * 512 + kc * 64);
    for (int e4 = 0; e4 < 16; e4++) {
        float4 w = w4[e4];
        #pragma unroll
        for (int n2 = 0; n2 < 4; n2++) {
            const float* a = aes + (ng * 4 + n2) * 64 + e4 * 4;
            acc[n2] += w.x * a[0] + w.y * a[1] + w.z * a[2] + w.w * a[3];
        }
    }
    float bias = (kc == 0) ? be[j] : 0.f;
    #pragma unroll
    for (int n2 = 0; n2 < 4; n2++)
        ctmp[((long long)kc * NB + ng * 4 + n2) * HATT + j] = acc[n2] + bias;
}

// ---------------- 5b. reduce2: ctmp[8][16][2048] -> ctmp2[16][2048] ------------
__global__ __launch_bounds__(256) void reduce2_kernel(
    const float* __restrict__ ctmp, float* __restrict__ ctmp2)
{
    int i = blockIdx.x * 256 + threadIdx.x;   // < 32768
    float s = 0.f;
    #pragma unroll
    for (int kc = 0; kc < 8; kc++)
        s += ctmp[(long long)kc * 32768 + i];
    ctmp2[i] = s;
}

// ---------------- 6. ctx_out (grid 128 = 32 ec x 4 nc) -------------------------
__global__ __launch_bounds__(256) void ctx_out_kernel(
    const float* __restrict__ ctmp2, const float* __restrict__ Wc,
    const float* __restrict__ bc, float* __restrict__ out_ctx)
{
    int ec = blockIdx.x & 31, nc = blockIdx.x >> 5;   // nc 0..3 (4 n each)
    int tid = threadIdx.x;
    __shared__ float ct[4 * 2048];        // 32 KB: ct[nn][j]
    __shared__ float red[16][4][17];      // [kq][nn][eo+pad]
    for (int i = tid; i < 4 * 2048; i += 256) {
        int nn = i >> 11, j = i & 2047;
        ct[i] = ctmp2[(nc * 4 + nn) * HATT + j];
    }
    __syncthreads();
    int eo = tid & 15, kq = tid >> 4;     // 16 eo x 16 K-slices (128 j each)
    int eg = ec * 16 + eo;
    float acc[4];
    #pragma unroll
    for (int nn = 0; nn < 4; nn++) acc[nn] = 0.f;
    const float4* w4 = (const float4*)(Wc + (long long)eg * HATT + kq * 128);
    for (int j4 = 0; j4 < 32; j4++) {
        float4 w = w4[j4];
        #pragma unroll
        for (int nn = 0; nn < 4; nn++) {
            const float* a = ct + nn * 2048 + kq * 128 + j4 * 4;
            acc[nn] += w.x * a[0] + w.y * a[1] + w.z * a[2] + w.w * a[3];
        }
    }
    #pragma unroll
    for (int nn = 0; nn < 4; nn++) red[kq][nn][eo] = acc[nn];
    __syncthreads();
    if (tid < 64) {
        int eo2 = tid & 15, nn2 = tid >> 4;   // 64 threads = 16 eo x 4 nn
        float s = 0.f;
        #pragma unroll
        for (int kq2 = 0; kq2 < 16; kq2++) s += red[kq2][nn2][eo2];
        out_ctx[((long long)(nc * 4 + nn2)) * 512 + ec * 16 + eo2] = s + bc[ec * 16 + eo2];
    }
}

// ---------------- launch ----------------
extern "C" void kernel_launch(void* const* d_in, const int* in_sizes, int n_in,
                              void* d_out, int out_size, void* d_ws, size_t ws_size,
                              hipStream_t stream)
{
    (void)in_sizes; (void)n_in; (void)out_size; (void)ws_size;
    const float* enc_pad  = (const float*)d_in[0];
    const int*   enc_len  = (const int*)  d_in[1];
    const float* dec_prev = (const float*)d_in[2];
    const float* ali_prev = (const float*)d_in[3];
    const float* We = (const float*)d_in[4];
    const float* be = (const float*)d_in[5];
    const float* Wk = (const float*)d_in[6];
    const float* Wd = (const float*)d_in[7];
    const float* WF = (const float*)d_in[8];
    const float* bF = (const float*)d_in[9];
    const float* Wa = (const float*)d_in[10];
    const float* Ww = (const float*)d_in[11];
    const float* Wc = (const float*)d_in[12];
    const float* bc = (const float*)d_in[13];

    char* ws = (char*)d_ws;
    u16*   Abf  = (u16*)  (ws);                 // 33,554,432 B (read thru a_enc)
    u16*   Wkbf = (u16*)  (ws + 33554432);      //  2,097,152 B (dead after gemm)
    u16*   ftb  = (u16*)  (ws + 35651584);      //  4,194,304 B (dead after gemm)
    u16*   wab  = (u16*)  (ws + 39845888);      //     65,536 B (dead after gemm)
    float* decp = (float*)(ws + 39911424);      //    524,288 B (dead after gemm)
    float* spart= (float*)(ws + 40435712);      //  2,097,152 B (dead after smax)
    float* aep  = (float*)(ws + 35651584);      // alias ftb   (4 MB fits)
    float* mstat= (float*)(ws + 39845888);      // alias wab   (2,048 B)
    float* scr  = (float*)(ws + 39911424);      // alias decp  (524,288 B exact)
    float* aep2 = (float*)(ws + 39911424);      // alias decp  (written after a_enc reads scr)
    float* ctmp = (float*)(ws + 40435712);      // alias spart (1 MB fits)
    float* ctmp2= (float*)(ws + 33554432);      // alias Wkbf  (131,072 B fits)
    // high-water 42,532,864 B (within proven 44.6 MB envelope)

    float* ali = (float*)d_out;                 // [16][4][2000]
    float* ctx = (float*)d_out + NB * HH * TT;  // [16][512]

    prep_kernel      <<<2468, 256, 0, stream>>>(enc_pad, Wk, ali_prev, WF, bF,
                                                dec_prev, Wd, Wa, enc_len,
                                                Abf, Wkbf, ftb, wab, decp);
    score_gemm_kernel<<<1024, 256, 0, stream>>>(Abf, Wkbf, ftb, wab, decp, Ww,
                                                enc_len, spart);
    smax_part_kernel <<<256,  256, 0, stream>>>(spart, enc_len, mstat, scr);
    a_enc_kernel     <<<512,  256, 0, stream>>>(scr, mstat, Abf, enc_len,
                                                aep, ali);
    reduce1_kernel   <<<128,  256, 0, stream>>>(aep, aep2);
    ctx_tmp_kernel   <<<256,  256, 0, stream>>>(aep2, We, be, ctmp);
    reduce2_kernel   <<<128,  256, 0, stream>>>(ctmp, ctmp2);
    ctx_out_kernel   <<<128,  256, 0, stream>>>(ctmp2, Wc, bc, ctx);
}

// Round 20
// 158.512 us; speedup vs baseline: 1.4108x; 1.4108x over previous
//
#include <hip/hip_runtime.h>

// ---------------- problem dims ----------------
#define NB   16
#define TT   2000
#define TP   2048      // padded T for GEMM tiling
#define SPT  2048      // spart row stride (padded for float4 loads)
#define ENC  512
#define ATTD 512
#define HH   4
#define CC   10
#define KK   64        // conv half-window
#define KW   129       // 2K+1
#define HATT 2048

typedef unsigned short u16;
typedef __attribute__((ext_vector_type(8))) short bf16x8;
typedef __attribute__((ext_vector_type(4))) float f32x4;

#define AS1 __attribute__((address_space(1)))
#define AS3 __attribute__((address_space(3)))

// convert geometry: 2176 blocks x 256 thr x 4 chunks x 8 elem
//   = 17,825,792 = NB*TP*ENC (1<<24) + 2048*512 (Wk) exactly
#define CVT_BLOCKS   2176
#define CVT_THREADS  (CVT_BLOCKS * 256)

// round-to-nearest-even f32 -> bf16, packed pair
__device__ inline unsigned bfpack2(float lo, float hi) {
    unsigned a = __builtin_bit_cast(unsigned, lo);
    unsigned b = __builtin_bit_cast(unsigned, hi);
    a = (a + 0x7fffu + ((a >> 16) & 1u)) >> 16;
    b = (b + 0x7fffu + ((b >> 16) & 1u)) >> 16;
    return a | (b << 16);
}

// ---------------- 1. fused prep: convert + conv_f(->bf16 f^T) + dec + Wa pack --
__global__ __launch_bounds__(256) void prep_kernel(
    const float* __restrict__ enc, const float* __restrict__ Wk,
    const float* __restrict__ ali_prev, const float* __restrict__ WF,
    const float* __restrict__ bF, const float* __restrict__ dec_prev,
    const float* __restrict__ Wd, const float* __restrict__ Wa,
    const int* __restrict__ enc_len,
    u16* __restrict__ Abf, u16* __restrict__ Wkbf,
    u16* __restrict__ ftb, u16* __restrict__ wab,
    float* __restrict__ decp)
{
    __shared__ union {
        struct { float aliW[632]; float wfT[KW * CC]; float bfs[CC]; } cv;
        float dsl[16 * 128];
    } sm;
    const int bid = blockIdx.x, tid = threadIdx.x;

    if (bid < CVT_BLOCKS) {
        // ---- bf16 convert; issue all 4 chunk loads before converts/stores ----
        const long long ATOT = (long long)NB * TP * ENC;   // 1<<24
        f32x4 v[4][2];
        bool live[4];
        long long g[4];
        #pragma unroll
        for (int it = 0; it < 4; it++) {
            long long cid = (long long)it * CVT_THREADS + bid * 256 + tid;
            long long gid = cid * 8;
            g[it] = gid;
            const float* s;
            bool valid = true;
            if (gid < ATOT) {
                int n = (int)(gid >> 20);
                int rem = (int)(gid & ((1 << 20) - 1));
                int r = rem >> 9, e = rem & 511;
                valid = (r < enc_len[n]);   // wave-uniform (one row per wave)
                s = enc + ((long long)n * TT + r) * ENC + e;
            } else {
                s = Wk + (gid - ATOT);      // < 2048*512
            }
            live[it] = valid;
            if (valid) {
                v[it][0] = __builtin_nontemporal_load((const f32x4*)s);
                v[it][1] = __builtin_nontemporal_load((const f32x4*)s + 1);
            }
        }
        #pragma unroll
        for (int it = 0; it < 4; it++) {
            if (!live[it]) continue;
            uint4 out;
            out.x = bfpack2(v[it][0].x, v[it][0].y);
            out.y = bfpack2(v[it][0].z, v[it][0].w);
            out.z = bfpack2(v[it][1].x, v[it][1].y);
            out.w = bfpack2(v[it][1].z, v[it][1].w);
            if (g[it] < ATOT) *(uint4*)(Abf + g[it]) = out;
            else              *(uint4*)(Wkbf + (g[it] - ATOT)) = out;
        }
    } else if (bid < CVT_BLOCKS + 256) {
        // ---- grouped conv1d, register accumulators; writes ftb[t][16] bf16 ----
        int b2 = bid - CVT_BLOCKS;
        int tc = b2 & 3, h = (b2 >> 2) & 3, n = b2 >> 4;
        int t0 = tc * 500;
        float* aliW = sm.cv.aliW;
        float* wfT  = sm.cv.wfT;       // [k][c] layout
        float* bfs  = sm.cv.bfs;
        const float* arow = ali_prev + ((long long)n * HH + h) * TT;
        for (int i = tid; i < 632; i += 256) {
            int tt = t0 - KK + i;
            aliW[i] = (tt >= 0 && tt < TT) ? arow[tt] : 0.f;
        }
        for (int i = tid; i < KW * CC; i += 256) {
            int k = i / CC, c = i - k * CC;
            wfT[i] = WF[(h * CC + c) * KW + k];
        }
        if (tid < CC) bfs[tid] = bF[h * CC + tid];
        __syncthreads();
        if (tid < 250) {
            float acc0[CC], acc1[CC];
            #pragma unroll
            for (int c = 0; c < CC; c++) { acc0[c] = 0.f; acc1[c] = 0.f; }
            const int base = 2 * tid;
            float2 w0 = *(const float2*)&aliW[base];
            for (int k = 0; k < 128; k += 2) {
                float2 w2 = *(const float2*)&aliW[base + k + 2];
                #pragma unroll
                for (int cj = 0; cj < 5; cj++) {
                    float2 fk  = *(const float2*)&wfT[k * CC + cj * 2];
                    float2 fk1 = *(const float2*)&wfT[(k + 1) * CC + cj * 2];
                    acc0[2*cj]   += w0.x * fk.x + w0.y * fk1.x;
                    acc0[2*cj+1] += w0.x * fk.y + w0.y * fk1.y;
                    acc1[2*cj]   += w0.y * fk.x + w2.x * fk1.x;
                    acc1[2*cj+1] += w0.y * fk.y + w2.x * fk1.y;
                }
                w0 = w2;
            }
            #pragma unroll
            for (int cj = 0; cj < 5; cj++) {
                float2 fk = *(const float2*)&wfT[128 * CC + cj * 2];
                acc0[2*cj]   += w0.x * fk.x;  acc0[2*cj+1] += w0.x * fk.y;
                acc1[2*cj]   += w0.y * fk.x;  acc1[2*cj+1] += w0.y * fk.y;
            }
            #pragma unroll
            for (int c = 0; c < CC; c++) { acc0[c] += bfs[c]; acc1[c] += bfs[c]; }
            int t = t0 + base;
            u16* frow = ftb + (((long long)(n * HH + h)) * TP + t) * 16;
            uint4 ra, rb;
            ra.x = bfpack2(acc0[0], acc0[1]); ra.y = bfpack2(acc0[2], acc0[3]);
            ra.z = bfpack2(acc0[4], acc0[5]); ra.w = bfpack2(acc0[6], acc0[7]);
            rb.x = bfpack2(acc0[8], acc0[9]); rb.y = 0u; rb.z = 0u; rb.w = 0u;
            *(uint4*)(frow)     = ra; *(uint4*)(frow + 8)  = rb;
            ra.x = bfpack2(acc1[0], acc1[1]); ra.y = bfpack2(acc1[2], acc1[3]);
            ra.z = bfpack2(acc1[4], acc1[5]); ra.w = bfpack2(acc1[6], acc1[7]);
            rb.x = bfpack2(acc1[8], acc1[9]);
            *(uint4*)(frow + 16) = ra; *(uint4*)(frow + 24) = rb;
        } else if (tc == 3) {
            // zero-pad ftb rows t in [2000, 2048)
            uint4 z = {0u, 0u, 0u, 0u};
            int r0 = 2000 + (tid - 250) * 8;
            u16* frow = ftb + (((long long)(n * HH + h)) * TP + r0) * 16;
            for (int r = 0; r < 8; r++) {
                *(uint4*)(frow + r * 16)     = z;
                *(uint4*)(frow + r * 16 + 8) = z;
            }
        }
    } else if (bid < CVT_BLOCKS + 288) {
        // ---- dec_part K-split partials: decp[kc][n][d] ----
        int b2 = bid - (CVT_BLOCKS + 256);   // 0..31
        int kc = b2 >> 3, jc = b2 & 7;
        for (int i = tid; i < 2048; i += 256) {
            int nn = i >> 7, kk = i & 127;
            sm.dsl[i] = dec_prev[nn * 512 + kc * 128 + kk];
        }
        __syncthreads();
        int d = jc * 256 + tid;
        float acc[NB];
        #pragma unroll
        for (int n = 0; n < NB; n++) acc[n] = 0.f;
        const float4* w4 = (const float4*)(Wd + (long long)d * 512 + kc * 128);
        for (int e4 = 0; e4 < 32; e4++) {
            float4 w = w4[e4];
            #pragma unroll
            for (int n = 0; n < NB; n++) {
                const float* a = sm.dsl + n * 128 + e4 * 4;
                acc[n] += w.x * a[0] + w.y * a[1] + w.z * a[2] + w.w * a[3];
            }
        }
        #pragma unroll
        for (int n = 0; n < NB; n++) decp[((long long)kc * NB + n) * HATT + d] = acc[n];
    } else {
        // ---- wab[j][16] = Wa[j>>9][j&511][0..9] bf16 (B-ext rows) ----
        int b2 = bid - (CVT_BLOCKS + 288);   // 0..3
        int j0 = b2 * 512 + tid * 2;
        #pragma unroll
        for (int q = 0; q < 2; q++) {
            int j = j0 + q;
            int hh = j >> 9, dd = j & 511;
            const float* wr = Wa + ((long long)(hh * ATTD + dd)) * CC;
            uint4 ra, rb;
            ra.x = bfpack2(wr[0], wr[1]); ra.y = bfpack2(wr[2], wr[3]);
            ra.z = bfpack2(wr[4], wr[5]); ra.w = bfpack2(wr[6], wr[7]);
            rb.x = bfpack2(wr[8], wr[9]); rb.y = 0u; rb.z = 0u; rb.w = 0u;
            u16* out = wab + (long long)j * 16;
            *(uint4*)(out)     = ra;
            *(uint4*)(out + 8) = rb;
        }
    }
}

// ---------------- 2. fused GEMM with att folded into K (K = 512 + 32ext) -------
// round-18 proven form: grid 4096, balanced XCD swizzle, ext tiles in regs,
// 32KB LDS, (256,4) -> no spill. (Persistent-loop variant spilled acc to
// scratch: 123MB WRITE, MfmaUtil 0.5% -- do not re-attempt.)
__global__ __launch_bounds__(256, 4) void score_gemm_kernel(
    const u16* __restrict__ Abf, const u16* __restrict__ Bbf,
    const u16* __restrict__ ftb, const u16* __restrict__ wab,
    const float* __restrict__ decp, const float* __restrict__ Ww,
    const int* __restrict__ enc_len, float* __restrict__ score_part)
{
    __shared__ __attribute__((aligned(16))) char smem[32768];  // lA 16K | lB 16K
    float* sred = (float*)smem;      // reused after final barrier

    const int bid = blockIdx.x;
    const int xcd = bid & 7;                 // physical XCD (round-robin dispatch)
    const int lcl = bid >> 3;                // 0..511 within XCD
    const int nt = lcl & 15;
    const int rr = lcl >> 4;                 // 0..31
    const int n = rr >> 1, half = rr & 1;
    const int mtl = (xcd + n) & 7;
    const int mt = half ? (8 + mtl) : mtl;

    if (mt * 128 >= enc_len[n]) return;   // fully-masked M-tile

    const int tid = threadIdx.x, wave = tid >> 6, lane = tid & 63;
    const int l16 = lane & 15, lk = lane >> 4;
    const int h = nt >> 2;

    const u16* Aptr = Abf + ((long long)n * TP + mt * 128) * ENC;
    const u16* Bptr = Bbf + (long long)nt * 128 * ENC;

    f32x4 acc[4][4];
    #pragma unroll
    for (int mi = 0; mi < 4; mi++)
        #pragma unroll
        for (int nj = 0; nj < 4; nj++) {
            f32x4 z = {0.f, 0.f, 0.f, 0.f};
            acc[mi][nj] = z;
        }

    const int wrow = (wave >> 1) * 64, wcol = (wave & 1) * 64;
    const int t0 = mt * 128, dd0 = (nt & 3) * 128;

    for (int kt = 0; kt < 8; kt++) {
        const int k0 = kt * 64;
        #pragma unroll
        for (int i = 0; i < 4; i++) {
            int b = i * 4096 + tid * 16;
            int r = b >> 7, kb = b & 127;
            int kbs = kb ^ ((r & 7) << 4);
            __builtin_amdgcn_global_load_lds(
                (const AS1 void*)(Aptr + r * ENC + k0 + (kbs >> 1)),
                (AS3 void*)(smem + i * 4096 + wave * 1024), 16, 0, 0);
            __builtin_amdgcn_global_load_lds(
                (const AS1 void*)(Bptr + r * ENC + k0 + (kbs >> 1)),
                (AS3 void*)(smem + 16384 + i * 4096 + wave * 1024), 16, 0, 0);
        }
        __syncthreads();
        #pragma unroll
        for (int ks = 0; ks < 64; ks += 32) {
            bf16x8 af[4], bf[4];
            #pragma unroll
            for (int mi = 0; mi < 4; mi++) {
                int row = wrow + mi * 16 + l16;
                int cb = (ks * 2 + lk * 16) ^ ((row & 7) << 4);
                af[mi] = *(const bf16x8*)(smem + row * 128 + cb);
            }
            #pragma unroll
            for (int nj = 0; nj < 4; nj++) {
                int row = wcol + nj * 16 + l16;
                int cb = (ks * 2 + lk * 16) ^ ((row & 7) << 4);
                bf[nj] = *(const bf16x8*)(smem + 16384 + row * 128 + cb);
            }
            #pragma unroll
            for (int mi = 0; mi < 4; mi++)
                #pragma unroll
                for (int nj = 0; nj < 4; nj++)
                    acc[mi][nj] = __builtin_amdgcn_mfma_f32_16x16x32_bf16(
                        af[mi], bf[nj], acc[mi][nj], 0, 0, 0);
        }
        __syncthreads();
    }

    // ---- K-extension step: att fold; ext fragments loaded straight to regs ----
    {
        bf16x8 zer = {0, 0, 0, 0, 0, 0, 0, 0};
        bf16x8 af[4], bf[4];
        #pragma unroll
        for (int mi = 0; mi < 4; mi++) af[mi] = zer;
        #pragma unroll
        for (int nj = 0; nj < 4; nj++) bf[nj] = zer;
        if (lk < 2) {
            #pragma unroll
            for (int mi = 0; mi < 4; mi++)
                af[mi] = *(const bf16x8*)(ftb +
                    (((long long)(n * HH + h)) * TP + t0 + wrow + mi * 16 + l16) * 16 + lk * 8);
            #pragma unroll
            for (int nj = 0; nj < 4; nj++)
                bf[nj] = *(const bf16x8*)(wab +
                    ((long long)(nt * 128 + wcol + nj * 16 + l16)) * 16 + lk * 8);
        }
        #pragma unroll
        for (int mi = 0; mi < 4; mi++)
            #pragma unroll
            for (int nj = 0; nj < 4; nj++)
                acc[mi][nj] = __builtin_amdgcn_mfma_f32_16x16x32_bf16(
                    af[mi], bf[nj], acc[mi][nj], 0, 0, 0);
    }

    // ---- epilogue: score'= sum_d -2*ww*rcp(exp(2v)+1)  (shift cancels in softmax)
    float wm2[4], dec4[4];
    #pragma unroll
    for (int nj = 0; nj < 4; nj++) {
        int cl = wcol + nj * 16 + l16;
        wm2[nj] = -2.f * Ww[h * ATTD + dd0 + cl];
        int j = nt * 128 + cl;
        dec4[nj] = decp[((long long)0 * NB + n) * HATT + j]
                 + decp[((long long)1 * NB + n) * HATT + j]
                 + decp[((long long)2 * NB + n) * HATT + j]
                 + decp[((long long)3 * NB + n) * HATT + j];
    }

    #pragma unroll
    for (int mi = 0; mi < 4; mi++) {
        #pragma unroll
        for (int j = 0; j < 4; j++) {
            int rl = wrow + mi * 16 + lk * 4 + j;
            float s = 0.f;
            #pragma unroll
            for (int nj = 0; nj < 4; nj++) {
                float v = acc[mi][nj][j] + dec4[nj];
                float e = __expf(v + v);
                s = fmaf(wm2[nj], __builtin_amdgcn_rcpf(e + 1.f), s);
            }
            s += __shfl_xor(s, 1); s += __shfl_xor(s, 2);
            s += __shfl_xor(s, 4); s += __shfl_xor(s, 8);
            if (l16 == 0) sred[(wave & 1) * 128 + rl] = s;
        }
    }
    __syncthreads();
    if (tid < 128) {
        int t = t0 + tid;
        if (t < TT)
            score_part[((long long)((nt & 3) * NB + n) * HH + h) * SPT + t] =
                sred[tid] + sred[128 + tid];
    }
}

// ---------------- 3. smax_part: partial (max,sum) + summed-score write ---------
// grid 256 = n(16) x h(4) x qr(4); each thread owns 2 consecutive t
__global__ __launch_bounds__(256) void smax_part_kernel(
    const float* __restrict__ score_part, const int* __restrict__ enc_len,
    float* __restrict__ mstat, float* __restrict__ scr)
{
    int qr = blockIdx.x & 3, h = (blockIdx.x >> 2) & 3, n = blockIdx.x >> 4;
    int len = enc_len[n];
    int tid = threadIdx.x;
    int t = qr * 512 + tid * 2;
    float s0 = 0.f, s1 = 0.f;
    #pragma unroll
    for (int q = 0; q < 4; q++) {
        float2 sv = *(const float2*)(score_part +
            (((long long)(q * NB + n)) * HH + h) * SPT + t);
        s0 += sv.x; s1 += sv.y;
    }
    {
        float2 o = {s0, s1};
        *(float2*)(scr + (n * HH + h) * SPT + t) = o;   // summed score for a_enc
    }
    bool v0 = (t < len), v1 = (t + 1 < len);
    float lmax = -3.4e38f;
    if (v0) lmax = s0;
    if (v1) lmax = fmaxf(lmax, s1);
    __shared__ float red[256];
    red[tid] = lmax; __syncthreads();
    for (int off = 128; off; off >>= 1) {
        if (tid < off) red[tid] = fmaxf(red[tid], red[tid + off]);
        __syncthreads();
    }
    float bmax = red[0];
    __syncthreads();
    float lsum = 0.f;
    if (v0) lsum += expf(s0 - bmax);
    if (v1) lsum += expf(s1 - bmax);
    red[tid] = lsum; __syncthreads();
    for (int off = 128; off; off >>= 1) {
        if (tid < off) red[tid] += red[tid + off];
        __syncthreads();
    }
    if (tid == 0) {
        float2 o = {bmax, red[0]};
        *(float2*)(mstat + ((n * HH + h) * 4 + qr) * 2) = o;
    }
}

// ---------------- 4. a_enc + inline softmax finish + ali write -----------------
// grid 512 = n(16) x tc(32); reads pre-summed scr (1 load instead of 4)
__global__ __launch_bounds__(256) void a_enc_kernel(
    const float* __restrict__ scr, const float* __restrict__ mstat,
    const u16* __restrict__ Abf, const int* __restrict__ enc_len,
    float* __restrict__ aep, float* __restrict__ ali)
{
    int tc = blockIdx.x & 31, n = blockIdx.x >> 5;
    int tid = threadIdx.x;
    int len = enc_len[n];
    int tbeg = tc * 63;
    int cnt = len - tbeg; if (cnt > 63) cnt = 63; if (cnt < 0) cnt = 0;
    __shared__ float aliS[HH][64];
    __shared__ float red[2][4][129];   // [tq][k][lane] transposed: conflict-free
    {
        int hh = tid >> 6, tt = tid & 63;
        int t = tbeg + tt;
        const float2* ms = (const float2*)(mstat) + (n * HH + hh) * 4;
        float2 p0 = ms[0], p1 = ms[1], p2 = ms[2], p3 = ms[3];
        float gm = fmaxf(fmaxf(p0.x, p1.x), fmaxf(p2.x, p3.x));
        float gs = p0.y * expf(p0.x - gm) + p1.y * expf(p1.x - gm)
                 + p2.y * expf(p2.x - gm) + p3.y * expf(p3.x - gm);
        float gi = 1.f / gs;
        float av = 0.f;
        if (tt < cnt) {
            float s = scr[(n * HH + hh) * SPT + t];
            av = expf(s - gm) * gi;
        }
        aliS[hh][tt] = av;
        if (tt < 63 && t < TT)
            ali[((long long)n * HH + hh) * TT + t] = av;
    }
    __syncthreads();
    const int l = tid & 127, tq = tid >> 7;   // dims 4l..4l+3; rows tl = 2*ii+tq
    float acc[HH][4];
    #pragma unroll
    for (int hh = 0; hh < HH; hh++)
        #pragma unroll
        for (int k = 0; k < 4; k++) acc[hh][k] = 0.f;
    #pragma unroll 4
    for (int ii = 0; ii < 32; ii++) {
        int tl = ii * 2 + tq;
        if (tl < cnt) {   // explicit guard: never touch unconverted rows
            uint2 u = *(const uint2*)(Abf + ((long long)n * TP + tbeg + tl) * ENC + l * 4);
            float e0 = __builtin_bit_cast(float, u.x << 16);
            float e1 = __builtin_bit_cast(float, u.x & 0xffff0000u);
            float e2 = __builtin_bit_cast(float, u.y << 16);
            float e3 = __builtin_bit_cast(float, u.y & 0xffff0000u);
            #pragma unroll
            for (int hh = 0; hh < HH; hh++) {
                float w = aliS[hh][tl];
                acc[hh][0] += w * e0; acc[hh][1] += w * e1;
                acc[hh][2] += w * e2; acc[hh][3] += w * e3;
            }
        }
    }
    #pragma unroll
    for (int hh = 0; hh < HH; hh++) {
        __syncthreads();
        #pragma unroll
        for (int k = 0; k < 4; k++) red[tq][k][l] = acc[hh][k];
        __syncthreads();
        int d2 = tid * 2;
        float v0 = red[0][d2 & 3][d2 >> 2] + red[1][d2 & 3][d2 >> 2];
        int d3 = d2 + 1;
        float v1 = red[0][d3 & 3][d3 >> 2] + red[1][d3 & 3][d3 >> 2];
        float2 o = {v0, v1};
        *(float2*)(aep + (((long long)tc * NB + n) * HH + hh) * ENC + d2) = o;
    }
}

// ---------------- 4b. reduce1: aep[32][16][4][512] -> aep2[16][4][512] ---------
__global__ __launch_bounds__(256) void reduce1_kernel(
    const float* __restrict__ aep, float* __restrict__ aep2)
{
    int i = blockIdx.x * 256 + threadIdx.x;   // < 32768
    float s = 0.f;
    for (int tc = 0; tc < 32; tc++)
        s += aep[(long long)tc * 32768 + i];
    aep2[i] = s;
}

// ---------------- 5. ctx_tmp partials (grid 256 = kc 8 x jc 32) ----------------
__global__ __launch_bounds__(256) void ctx_tmp_kernel(
    const float* __restrict__ aep2, const float* __restrict__ We,
    const float* __restrict__ be, float* __restrict__ ctmp)
{
    int kc = blockIdx.x >> 5, jc = blockIdx.x & 31;  // kc 0..7 (64-K), jc 0..31
    int tid = threadIdx.x;
    int h = (jc * 64) >> 9;               // uniform per block (64 j per block)
    __shared__ float aes[16 * 64];
    for (int i = tid; i < 1024; i += 256) {
        int nn = i >> 6, kk = i & 63;
        aes[i] = aep2[(nn * HH + h) * ENC + kc * 64 + kk];
    }
    __syncthreads();
    int j = jc * 64 + (tid & 63);
    int ng = tid >> 6;                    // n-group: n = ng*4 .. ng*4+3
    float acc[4];
    #pragma unroll
    for (int n2 = 0; n2 < 4; n2++) acc[n2] = 0.f;
    const float4* w4 = (const float4*)(We + (long long)j * 512 + kc * 64);
    for (int e4 = 0; e4 < 16; e4++) {
        float4 w = w4[e4];
        #pragma unroll
        for (int n2 = 0; n2 < 4; n2++) {
            const float* a = aes + (ng * 4 + n2) * 64 + e4 * 4;
            acc[n2] += w.x * a[0] + w.y * a[1] + w.z * a[2] + w.w * a[3];
        }
    }
    float bias = (kc == 0) ? be[j] : 0.f;
    #pragma unroll
    for (int n2 = 0; n2 < 4; n2++)
        ctmp[((long long)kc * NB + ng * 4 + n2) * HATT + j] = acc[n2] + bias;
}

// ---------------- 5b. reduce2: ctmp[8][16][2048] -> ctmp2[16][2048] ------------
__global__ __launch_bounds__(256) void reduce2_kernel(
    const float* __restrict__ ctmp, float* __restrict__ ctmp2)
{
    int i = blockIdx.x * 256 + threadIdx.x;   // < 32768
    float s = 0.f;
    #pragma unroll
    for (int kc = 0; kc < 8; kc++)
        s += ctmp[(long long)kc * 32768 + i];
    ctmp2[i] = s;
}

// ---------------- 6. ctx_out (grid 128 = 32 ec x 4 nc) -------------------------
__global__ __launch_bounds__(256) void ctx_out_kernel(
    const float* __restrict__ ctmp2, const float* __restrict__ Wc,
    const float* __restrict__ bc, float* __restrict__ out_ctx)
{
    int ec = blockIdx.x & 31, nc = blockIdx.x >> 5;   // nc 0..3 (4 n each)
    int tid = threadIdx.x;
    __shared__ float ct[4 * 2048];        // 32 KB: ct[nn][j]
    __shared__ float red[16][4][17];      // [kq][nn][eo+pad]
    for (int i = tid; i < 4 * 2048; i += 256) {
        int nn = i >> 11, j = i & 2047;
        ct[i] = ctmp2[(nc * 4 + nn) * HATT + j];
    }
    __syncthreads();
    int eo = tid & 15, kq = tid >> 4;     // 16 eo x 16 K-slices (128 j each)
    int eg = ec * 16 + eo;
    float acc[4];
    #pragma unroll
    for (int nn = 0; nn < 4; nn++) acc[nn] = 0.f;
    const float4* w4 = (const float4*)(Wc + (long long)eg * HATT + kq * 128);
    for (int j4 = 0; j4 < 32; j4++) {
        float4 w = w4[j4];
        #pragma unroll
        for (int nn = 0; nn < 4; nn++) {
            const float* a = ct + nn * 2048 + kq * 128 + j4 * 4;
            acc[nn] += w.x * a[0] + w.y * a[1] + w.z * a[2] + w.w * a[3];
        }
    }
    #pragma unroll
    for (int nn = 0; nn < 4; nn++) red[kq][nn][eo] = acc[nn];
    __syncthreads();
    if (tid < 64) {
        int eo2 = tid & 15, nn2 = tid >> 4;   // 64 threads = 16 eo x 4 nn
        float s = 0.f;
        #pragma unroll
        for (int kq2 = 0; kq2 < 16; kq2++) s += red[kq2][nn2][eo2];
        out_ctx[((long long)(nc * 4 + nn2)) * 512 + ec * 16 + eo2] = s + bc[ec * 16 + eo2];
    }
}

// ---------------- launch ----------------
extern "C" void kernel_launch(void* const* d_in, const int* in_sizes, int n_in,
                              void* d_out, int out_size, void* d_ws, size_t ws_size,
                              hipStream_t stream)
{
    (void)in_sizes; (void)n_in; (void)out_size; (void)ws_size;
    const float* enc_pad  = (const float*)d_in[0];
    const int*   enc_len  = (const int*)  d_in[1];
    const float* dec_prev = (const float*)d_in[2];
    const float* ali_prev = (const float*)d_in[3];
    const float* We = (const float*)d_in[4];
    const float* be = (const float*)d_in[5];
    const float* Wk = (const float*)d_in[6];
    const float* Wd = (const float*)d_in[7];
    const float* WF = (const float*)d_in[8];
    const float* bF = (const float*)d_in[9];
    const float* Wa = (const float*)d_in[10];
    const float* Ww = (const float*)d_in[11];
    const float* Wc = (const float*)d_in[12];
    const float* bc = (const float*)d_in[13];

    char* ws = (char*)d_ws;
    u16*   Abf  = (u16*)  (ws);                 // 33,554,432 B (read thru a_enc)
    u16*   Wkbf = (u16*)  (ws + 33554432);      //  2,097,152 B (dead after gemm)
    u16*   ftb  = (u16*)  (ws + 35651584);      //  4,194,304 B (dead after gemm)
    u16*   wab  = (u16*)  (ws + 39845888);      //     65,536 B (dead after gemm)
    float* decp = (float*)(ws + 39911424);      //    524,288 B (dead after gemm)
    float* spart= (float*)(ws + 40435712);      //  2,097,152 B (dead after smax)
    float* aep  = (float*)(ws + 35651584);      // alias ftb   (4 MB fits)
    float* mstat= (float*)(ws + 39845888);      // alias wab   (2,048 B)
    float* scr  = (float*)(ws + 39911424);      // alias decp  (524,288 B exact)
    float* aep2 = (float*)(ws + 39911424);      // alias decp  (written after a_enc reads scr)
    float* ctmp = (float*)(ws + 40435712);      // alias spart (1 MB fits)
    float* ctmp2= (float*)(ws + 33554432);      // alias Wkbf  (131,072 B fits)
    // high-water 42,532,864 B (within proven 44.6 MB envelope)

    float* ali = (float*)d_out;                 // [16][4][2000]
    float* ctx = (float*)d_out + NB * HH * TT;  // [16][512]

    prep_kernel      <<<2468, 256, 0, stream>>>(enc_pad, Wk, ali_prev, WF, bF,
                                                dec_prev, Wd, Wa, enc_len,
                                                Abf, Wkbf, ftb, wab, decp);
    score_gemm_kernel<<<4096, 256, 0, stream>>>(Abf, Wkbf, ftb, wab, decp, Ww,
                                                enc_len, spart);
    smax_part_kernel <<<256,  256, 0, stream>>>(spart, enc_len, mstat, scr);
    a_enc_kernel     <<<512,  256, 0, stream>>>(scr, mstat, Abf, enc_len,
                                                aep, ali);
    reduce1_kernel   <<<128,  256, 0, stream>>>(aep, aep2);
    ctx_tmp_kernel   <<<256,  256, 0, stream>>>(aep2, We, be, ctmp);
    reduce2_kernel   <<<128,  256, 0, stream>>>(ctmp, ctmp2);
    ctx_out_kernel   <<<128,  256, 0, stream>>>(ctmp2, Wc, bc, ctx);
}